// Round 8
// baseline (165.331 us; speedup 1.0000x reference)
//
#include <hip/hip_runtime.h>
#include <hip/hip_bf16.h>
#include <math.h>

// ---------------------------------------------------------------------------
// out[s] = (sum_i gate_i * x_i) @ Wm + (sum_i gate_i) * bm
// gate_i = softmax-with-eps over h_i = x_i.Wg + bg + pow*ln(w_i)
// index is SORTED -> segments are contiguous row ranges.
// ---------------------------------------------------------------------------

// K1: seg_start[s] = first row i with index[i] >= s ; seg_start[S] = N
__global__ __launch_bounds__(256) void k1_seg_offsets(const int* __restrict__ index,
                                                      int* __restrict__ seg_start,
                                                      int N, int S) {
    int i = blockIdx.x * blockDim.x + threadIdx.x;
    if (i >= N) return;
    int cur  = index[i];
    int prev = (i == 0) ? -1 : index[i - 1];
    for (int s = prev + 1; s <= cur; ++s) seg_start[s] = i;
    if (i == N - 1) {
        for (int s = cur + 1; s <= S; ++s) seg_start[s] = N;
    }
}

// K2: one wave per segment (oversubscribed -> HW self-balancing).
// CONTIGUOUS-INSTRUCTION layout: one load instr = 1 KB = 2 complete rows
// (lanes 0-31 = row r, lanes 32-63 = row r+1; each lane a float4 slice).
// Per 4-row step: loads A (rows r,r+1) + B (rows r+2,r+3). Two independent
// online-softmax streams (one per 32-lane half), 5-level shfl_xor row-dot,
// defer-rescale (THR=8); halves flash-combined once at the end.
// Burst-issue up to 6 steps (24 rows) then drain; rare tail loop beyond.

#define K2_ISSUE(s, Ak, Bk, WAk, WBk)                                         \
    {   int r0_ = start + 4 * (s);                                            \
        int rA_ = r0_ + half;     if (rA_ > lastrow) rA_ = lastrow;           \
        int rB_ = r0_ + 2 + half; if (rB_ > lastrow) rB_ = lastrow;           \
        Ak  = *reinterpret_cast<const float4*>(x + (size_t)rA_ * 128 + sl4);  \
        Bk  = *reinterpret_cast<const float4*>(x + (size_t)rB_ * 128 + sl4);  \
        WAk = wt[rA_]; WBk = wt[rB_]; }

#define K2_COMP(s, Ak, Bk, WAk, WBk)                                          \
    {   int r0_ = start + 4 * (s);                                            \
        bool vA = (r0_ + half) < end;                                         \
        bool vB = (r0_ + 2 + half) < end;                                     \
        float dA = Ak.x*wgv.x + Ak.y*wgv.y + Ak.z*wgv.z + Ak.w*wgv.w;         \
        float dB = Bk.x*wgv.x + Bk.y*wgv.y + Bk.z*wgv.z + Bk.w*wgv.w;         \
        dA += __shfl_xor(dA, 1);  dB += __shfl_xor(dB, 1);                    \
        dA += __shfl_xor(dA, 2);  dB += __shfl_xor(dB, 2);                    \
        dA += __shfl_xor(dA, 4);  dB += __shfl_xor(dB, 4);                    \
        dA += __shfl_xor(dA, 8);  dB += __shfl_xor(dB, 8);                    \
        dA += __shfl_xor(dA, 16); dB += __shfl_xor(dB, 16);                   \
        float hA = vA ? (dA + fmaf(pw, __logf(WAk), bgv)) : -1e30f;           \
        float hB = vB ? (dB + fmaf(pw, __logf(WBk), bgv)) : -1e30f;           \
        float hm = fmaxf(hA, hB);                                             \
        if (hm > mg + 8.f) {                                                  \
            float sc = __expf(mg - hm);                                       \
            ssum *= sc;                                                       \
            acc.x *= sc; acc.y *= sc; acc.z *= sc; acc.w *= sc;               \
            mg = hm; }                                                        \
        float eA = vA ? __expf(hA - mg) : 0.f;                                \
        float eB = vB ? __expf(hB - mg) : 0.f;                                \
        ssum += eA + eB;                                                      \
        acc.x += eA * Ak.x + eB * Bk.x;                                       \
        acc.y += eA * Ak.y + eB * Bk.y;                                       \
        acc.z += eA * Ak.z + eB * Bk.z;                                       \
        acc.w += eA * Ak.w + eB * Bk.w; }

__global__ __launch_bounds__(256) void k2_seg_softmax_pool(
    const float* __restrict__ x, const float* __restrict__ wt,
    const float* __restrict__ Wg, const float* __restrict__ bg,
    const float* __restrict__ pw_, const int* __restrict__ seg_start,
    float* __restrict__ t, float* __restrict__ sgate, int N, int S) {
    int gwid = (int)((blockIdx.x * 256 + threadIdx.x) >> 6);
    if (gwid >= S) return;
    int lane = threadIdx.x & 63;
    int half = lane >> 5;        // 0: even row of pair, 1: odd row
    int sl   = lane & 31;        // feature slice [4*sl, 4*sl+4)
    int sl4  = sl * 4;

    int start = seg_start[gwid], end = seg_start[gwid + 1];

    if (start >= end) {          // empty segment: exact zeros
        if (lane < 32)
            *reinterpret_cast<float4*>(t + (size_t)gwid * 128 + sl4) =
                make_float4(0.f, 0.f, 0.f, 0.f);
        if (lane == 0) sgate[gwid] = 0.f;
        return;
    }

    float4 wgv = *reinterpret_cast<const float4*>(Wg + sl4);
    float bgv = bg[0];
    float pw  = pw_[0];

    int nsteps  = (end - start + 3) >> 2;
    int lastrow = N - 1;         // memory clamp only; validity via `end`

    float4 A0,B0,A1,B1,A2,B2,A3,B3,A4,B4,A5,B5;
    float  WA0,WB0,WA1,WB1,WA2,WB2,WA3,WB3,WA4,WB4,WA5,WB5;

    // ---- burst-issue (gated to limit over-fetch; pairs with drain guards) --
    K2_ISSUE(0, A0, B0, WA0, WB0);
    K2_ISSUE(1, A1, B1, WA1, WB1);
    if (nsteps > 2) {
        K2_ISSUE(2, A2, B2, WA2, WB2);
        K2_ISSUE(3, A3, B3, WA3, WB3);
    }
    if (nsteps > 4) {
        K2_ISSUE(4, A4, B4, WA4, WB4);
        K2_ISSUE(5, A5, B5, WA5, WB5);
    }

    float mg = -INFINITY, ssum = 0.f;
    float4 acc = make_float4(0.f, 0.f, 0.f, 0.f);

    // ---- drain ----
    K2_COMP(0, A0, B0, WA0, WB0);
    if (nsteps > 1) {
        K2_COMP(1, A1, B1, WA1, WB1);
        if (nsteps > 2) {
            K2_COMP(2, A2, B2, WA2, WB2);
            if (nsteps > 3) {
                K2_COMP(3, A3, B3, WA3, WB3);
                if (nsteps > 4) {
                    K2_COMP(4, A4, B4, WA4, WB4);
                    if (nsteps > 5) {
                        K2_COMP(5, A5, B5, WA5, WB5);
                        for (int s = 6; s < nsteps; ++s) {   // rare: >24 rows
                            K2_ISSUE(s, A0, B0, WA0, WB0);
                            K2_COMP(s, A0, B0, WA0, WB0);
                        }
                    }
                }
            }
        }
    }

    // ---- flash-combine the two 32-lane halves (xor 32) ----
    {
        float mo = __shfl_xor(mg, 32);
        float so = __shfl_xor(ssum, 32);
        float ax = __shfl_xor(acc.x, 32), ay = __shfl_xor(acc.y, 32);
        float az = __shfl_xor(acc.z, 32), aw = __shfl_xor(acc.w, 32);
        float mc = fmaxf(mg, mo);
        float c1 = (mg > -1e29f) ? __expf(mg - mc) : 0.f;   // sentinel guard
        float c2 = (mo > -1e29f) ? __expf(mo - mc) : 0.f;
        ssum = ssum * c1 + so * c2;
        acc.x = acc.x * c1 + ax * c2;
        acc.y = acc.y * c1 + ay * c2;
        acc.z = acc.z * c1 + az * c2;
        acc.w = acc.w * c1 + aw * c2;
    }

    float inv = 1.f / (ssum + 1e-10f);
    if (lane < 32) {
        *reinterpret_cast<float4*>(t + (size_t)gwid * 128 + sl4) =
            make_float4(acc.x * inv, acc.y * inv, acc.z * inv, acc.w * inv);
    }
    if (lane == 0) sgate[gwid] = ssum * inv;   // sum of normalized gates
}

// K3: out[row][:] = t[row][:] @ Wm + sgate[row] * bm
// 512 threads: 8 waves x 8 rows = 64 rows/block; Wm staged once in 64 KiB LDS.
__global__ __launch_bounds__(512) void k3_out_gemm(
    const float* __restrict__ t, const float* __restrict__ Wm,
    const float* __restrict__ bm, const float* __restrict__ sgate,
    float* __restrict__ out, int S) {
    __shared__ float2 lwm[128][64];   // lwm[k][l] = (Wm[k][l], Wm[k][l+64])
    int tid = threadIdx.x;
    for (int idx = tid; idx < 128 * 64; idx += 512) {
        int k = idx >> 6, l = idx & 63;
        lwm[k][l] = make_float2(Wm[k * 128 + l], Wm[k * 128 + 64 + l]);
    }
    __syncthreads();

    int wave = tid >> 6, lane = tid & 63;
    int row0 = (blockIdx.x * 8 + wave) * 8;       // 8 rows per wave
    if (row0 >= S) return;

    const float* tb = t + (size_t)__builtin_amdgcn_readfirstlane(row0) * 128;

    float accx[8], accy[8];
    #pragma unroll
    for (int r = 0; r < 8; ++r) { accx[r] = 0.f; accy[r] = 0.f; }

    for (int k = 0; k < 128; k += 4) {
        float2 w0 = lwm[k][lane],     w1 = lwm[k + 1][lane];
        float2 w2 = lwm[k + 2][lane], w3 = lwm[k + 3][lane];
        #pragma unroll
        for (int r = 0; r < 8; ++r) {
            const float* tr = tb + r * 128 + k;   // uniform -> s_load
            float t0 = tr[0], t1 = tr[1], t2 = tr[2], t3 = tr[3];
            accx[r] += t0 * w0.x; accy[r] += t0 * w0.y;
            accx[r] += t1 * w1.x; accy[r] += t1 * w1.y;
            accx[r] += t2 * w2.x; accy[r] += t2 * w2.y;
            accx[r] += t3 * w3.x; accy[r] += t3 * w3.y;
        }
    }

    float bmx = bm[lane], bmy = bm[lane + 64];
    #pragma unroll
    for (int r = 0; r < 8; ++r) {
        int row = row0 + r;
        if (row < S) {
            float sg = sgate[row];
            out[(size_t)row * 128 + lane]      = accx[r] + sg * bmx;
            out[(size_t)row * 128 + lane + 64] = accy[r] + sg * bmy;
        }
    }
}

extern "C" void kernel_launch(void* const* d_in, const int* in_sizes, int n_in,
                              void* d_out, int out_size, void* d_ws, size_t ws_size,
                              hipStream_t stream) {
    const float* x       = (const float*)d_in[0];
    const float* weights = (const float*)d_in[1];
    const float* Wg      = (const float*)d_in[2];
    const float* bg      = (const float*)d_in[3];
    const float* Wm      = (const float*)d_in[4];
    const float* bm      = (const float*)d_in[5];
    const float* pow_    = (const float*)d_in[6];
    const int*   index   = (const int*)d_in[7];
    float* out = (float*)d_out;

    int N = in_sizes[1];          // weights is [N,1]
    int S = out_size / 128;       // out is [S,128]

    // workspace layout
    char* ws = (char*)d_ws;
    int* seg_start = (int*)ws;                                  // (S+1) ints
    size_t off = (((size_t)(S + 1) * 4) + 255) & ~(size_t)255;
    float* sgate = (float*)(ws + off);                          // S floats
    off += (((size_t)S * 4) + 255) & ~(size_t)255;
    float* t = (float*)(ws + off);                              // (S+64)*128 floats (pad for K3 over-read)

    k1_seg_offsets<<<(N + 255) / 256, 256, 0, stream>>>(index, seg_start, N, S);
    k2_seg_softmax_pool<<<(S + 3) / 4, 256, 0, stream>>>(x, weights, Wg, bg, pow_,
                                                         seg_start, t, sgate, N, S);
    k3_out_gemm<<<(S + 63) / 64, 512, 0, stream>>>(t, Wm, bm, sgate, out, S);
}